// Round 3
// baseline (386.352 us; speedup 1.0000x reference)
//
#include <hip/hip_runtime.h>
#include <math.h>

// ---------------------------------------------------------------------------
// GCN layer: out = tanh( scatter_add(adj_vals * h[src] -> dst)
//                        + seq @ w_proj + b_proj + bias ),   h = seq @ w_fc
// N=100000, E=1600000, D=128, fp32.
// R8 -> R9:
//  * agg R8 post-mortem: VALU 42->33% but dur flat -> memory-side bound
//    (latency or LLC cap), not VALU. Restructured gather: 16 lanes x 16B
//    per edge row, 4 edges per dwordx4 instruction (1KB/instr), explicit
//    1-batch software pipeline, butterfly (shfl_xor 16/32) group reduce.
//    Bytes unchanged -> discriminates latency-bound vs BW-cap.
//  * mm kernels persistent: grid 512, tile-stride loop; W LDS-stage
//    amortized ~3x (was re-staged by all 1563 blocks).
// ---------------------------------------------------------------------------

typedef __attribute__((ext_vector_type(8))) short short8;
typedef __attribute__((ext_vector_type(4))) float float4v;
typedef __attribute__((ext_vector_type(2))) _Float16 half2v;

#define PG 256          // partition blocks (slices)
#define NBMAX 2048      // max buckets (64 nodes each)

static __device__ __forceinline__ short f2bf(float x) {
    unsigned u = __float_as_uint(x);
    unsigned r = (u + 0x7fffu + ((u >> 16) & 1u)) >> 16;   // RNE
    return (short)r;
}
static __device__ __forceinline__ float bf2f(short h) {
    return __uint_as_float(((unsigned)(unsigned short)h) << 16);
}

// ---------------- W pre-conversion: w[k][c] fp32 -> whi/wlo[c][k] bf16 ------
// One launch converts both weight matrices (blocks 0-15: w_fc, 16-31: w_proj).
__global__ __launch_bounds__(256)
void wconv_kernel(const float* __restrict__ wa, const float* __restrict__ wb,
                  short* __restrict__ whia, short* __restrict__ wloa,
                  short* __restrict__ whib, short* __restrict__ wlob) {
    const int bb = blockIdx.x;
    const float* w  = (bb < 16) ? wa   : wb;
    short* whi      = (bb < 16) ? whia : whib;
    short* wlo      = (bb < 16) ? wloa : wlob;
    const int i = (bb & 15) * 256 + threadIdx.x;    // 4096 float4s
    const float4 v = ((const float4*)w)[i];
    const int k = i >> 5;
    const int c4 = (i & 31) * 4;
    float xs[4] = {v.x, v.y, v.z, v.w};
    #pragma unroll
    for (int j = 0; j < 4; j++) {
        const short hi = f2bf(xs[j]);
        const short lo = f2bf(xs[j] - bf2f(hi));
        whi[(c4 + j) * 128 + k] = hi;
        wlo[(c4 + j) * 128 + k] = lo;
    }
}

// ---------------- MFMA matmul: out[N x 128] = seq[N x 128] @ w[128 x 128] ---
// A*B ~= Ah*Bh + Ah*Bl + Al*Bh (split bf16, rel err ~1e-5).
// out16 != nullptr -> store fp16 (h path); else fp32 + bias (proj path).
// Persistent: each block stages W once, then tile-strides.
#define KP 136

__global__ __launch_bounds__(256, 2)
void mm_mfma_kernel(const float* __restrict__ seq, const short* __restrict__ whi,
                    const short* __restrict__ wlo,
                    const float* __restrict__ b0p, const float* __restrict__ b1p,
                    float* __restrict__ out, _Float16* __restrict__ out16,
                    int N, int add_bias, int ntiles) {
    __shared__ short wt_hi[128 * KP];
    __shared__ short wt_lo[128 * KP];

    const int tid = threadIdx.x;
    for (int i = tid; i < 2048; i += 256) {
        const int row = i >> 4;
        const int k8  = (i & 15) * 8;
        *(float4*)&wt_hi[row * KP + k8] = ((const float4*)whi)[i];
        *(float4*)&wt_lo[row * KP + k8] = ((const float4*)wlo)[i];
    }
    __syncthreads();

    const int wave = tid >> 6;
    const int lane = tid & 63;
    const int q = lane >> 4;
    const int c = lane & 15;

    for (int tile = blockIdx.x; tile < ntiles; tile += gridDim.x) {
        const int R = tile * 64 + wave * 16;
        const int rowL = (R + c < N) ? (R + c) : (N - 1);

        float4v acc[8];
        #pragma unroll
        for (int ct = 0; ct < 8; ct++) acc[ct] = (float4v){0.f, 0.f, 0.f, 0.f};

        #pragma unroll
        for (int t = 0; t < 4; t++) {
            const int kk = t * 32 + q * 8;
            const float4 a0 = *(const float4*)&seq[(size_t)rowL * 128 + kk];
            const float4 a1 = *(const float4*)&seq[(size_t)rowL * 128 + kk + 4];
            float xs[8] = {a0.x, a0.y, a0.z, a0.w, a1.x, a1.y, a1.z, a1.w};
            union { short s[8]; short8 v; } ahi, alo;
            #pragma unroll
            for (int j = 0; j < 8; j++) {
                const short hi = f2bf(xs[j]);
                ahi.s[j] = hi;
                alo.s[j] = f2bf(xs[j] - bf2f(hi));
            }
            #pragma unroll
            for (int ct = 0; ct < 8; ct++) {
                const int n = ct * 16 + c;
                const short8 bhi = *(const short8*)&wt_hi[n * KP + kk];
                const short8 blo = *(const short8*)&wt_lo[n * KP + kk];
                acc[ct] = __builtin_amdgcn_mfma_f32_16x16x32_bf16(ahi.v, bhi, acc[ct], 0, 0, 0);
                acc[ct] = __builtin_amdgcn_mfma_f32_16x16x32_bf16(ahi.v, blo, acc[ct], 0, 0, 0);
                acc[ct] = __builtin_amdgcn_mfma_f32_16x16x32_bf16(alo.v, bhi, acc[ct], 0, 0, 0);
            }
        }

        if (out16) {
            #pragma unroll
            for (int ct = 0; ct < 8; ct++) {
                const int col = ct * 16 + c;
                #pragma unroll
                for (int r = 0; r < 4; r++) {
                    const int row = R + q * 4 + r;
                    if (row < N) out16[(size_t)row * 128 + col] = (_Float16)acc[ct][r];
                }
            }
        } else {
            #pragma unroll
            for (int ct = 0; ct < 8; ct++) {
                const int col = ct * 16 + c;
                float badd = 0.f;
                if (add_bias) badd = b0p[col] + b1p[col];
                #pragma unroll
                for (int r = 0; r < 4; r++) {
                    const int row = R + q * 4 + r;
                    if (row < N) out[(size_t)row * 128 + col] = acc[ct][r] + badd;
                }
            }
        }
    }
}

// ---------------- atomic-free radix partition (bucket = dst>>6) ------------

// Per-slice LDS histogram -> hcnt[b*PG + g] (bucket-major for the scan).
__global__ __launch_bounds__(256)
void phist_kernel(const int* __restrict__ edst, int* __restrict__ hcnt,
                  int E, int S, int NB) {
    __shared__ int cnt[NBMAX];
    const int g = blockIdx.x;
    const int tid = threadIdx.x;
    for (int b = tid; b < NB; b += 256) cnt[b] = 0;
    __syncthreads();
    const int lo = g * S;
    const int hi = (lo + S < E) ? (lo + S) : E;
    for (int i = lo + tid; i < hi; i += 256)
        atomicAdd(&cnt[edst[i] >> 6], 1);
    __syncthreads();
    for (int b = tid; b < NB; b += 256) hcnt[b * PG + g] = cnt[b];
}

// Exclusive scan over L = NB*PG entries. pscan1: per-block (2048 elems)
// exclusive prefix + block sums.
__global__ __launch_bounds__(256)
void pscan1_kernel(const int* __restrict__ in, int* __restrict__ out,
                   int* __restrict__ bsum, int L) {
    __shared__ int s[256];
    const int t = threadIdx.x;
    const int base = blockIdx.x * 2048 + t * 8;
    int v[8];
    int mysum = 0;
    #pragma unroll
    for (int j = 0; j < 8; j++) {
        v[j] = (base + j < L) ? in[base + j] : 0;
        mysum += v[j];
    }
    s[t] = mysum;
    __syncthreads();
    for (int o = 1; o < 256; o <<= 1) {
        int add = (t >= o) ? s[t - o] : 0;
        __syncthreads();
        s[t] += add;
        __syncthreads();
    }
    int run = s[t] - mysum;
    #pragma unroll
    for (int j = 0; j < 8; j++) {
        if (base + j < L) out[base + j] = run;
        run += v[j];
    }
    if (t == 255) bsum[blockIdx.x] = s[255];
}

// Single block: exclusive scan of nb (<=256) block sums.
__global__ __launch_bounds__(256)
void pscan2_kernel(const int* __restrict__ bsum, int* __restrict__ ebsum, int nb) {
    __shared__ int s[256];
    const int t = threadIdx.x;
    const int v = (t < nb) ? bsum[t] : 0;
    s[t] = v;
    __syncthreads();
    for (int o = 1; o < 256; o <<= 1) {
        int add = (t >= o) ? s[t - o] : 0;
        __syncthreads();
        s[t] += add;
        __syncthreads();
    }
    if (t < nb) ebsum[t] = s[t] - v;
}

// pos[i] += ebsum[block]; also emit bstart[b] = pos[b*PG] and bstart[NB] = E.
__global__ __launch_bounds__(256)
void paddback_kernel(int* __restrict__ pos, const int* __restrict__ ebsum,
                     int* __restrict__ bstart, int L, int NB, int E) {
    const int add = ebsum[blockIdx.x];
    const int base = blockIdx.x * 2048 + threadIdx.x * 8;
    #pragma unroll
    for (int j = 0; j < 8; j++) {
        const int idx = base + j;
        if (idx < L) {
            const int v = pos[idx] + add;
            pos[idx] = v;
            if ((idx & (PG - 1)) == 0) bstart[idx / PG] = v;
        }
    }
    if (blockIdx.x == 0 && threadIdx.x == 0) bstart[NB] = E;
}

// Atomic-free (global) scatter: LDS cursors seeded from pos.
// entry = (src<<6 | dst&63, val) : 8B.
__global__ __launch_bounds__(256)
void pscatter_kernel(const int* __restrict__ esrc, const int* __restrict__ edst,
                     const float* __restrict__ vals, const int* __restrict__ pos,
                     int2* __restrict__ sedge, int E, int S, int NB) {
    __shared__ int cur[NBMAX];
    const int g = blockIdx.x;
    const int tid = threadIdx.x;
    for (int b = tid; b < NB; b += 256) cur[b] = pos[b * PG + g];
    __syncthreads();
    const int lo = g * S;
    const int hi = (lo + S < E) ? (lo + S) : E;
    for (int i = lo + tid; i < hi; i += 256) {
        const int d = edst[i];
        const int p = atomicAdd(&cur[d >> 6], 1);
        sedge[p] = make_int2((esrc[i] << 6) | (d & 63), __float_as_int(vals[i]));
    }
}

// One block (256 thr) per 64-node bucket. Counting-sort edges by node into
// LDS (16KB), then each wave aggregates 16 nodes. Gather layout: 16 lanes
// per edge row (16B each), 4 edges per dwordx4 instruction, 1-batch software
// pipeline; group-reduce via shfl_xor(16/32) butterfly. Fused tanh; out RMW
// non-temporal.
#define CAP 2048

__global__ __launch_bounds__(256, 8)
void aggregate_sorted(const int* __restrict__ bstart, const int2* __restrict__ sedge,
                      const _Float16* __restrict__ h, float* __restrict__ out, int N) {
    __shared__ int2 ebuf[CAP];
    __shared__ int cnt[64], sc[64], off[65], cur[64];
    const int b = blockIdx.x;
    const int tid = threadIdx.x;
    const int beg = bstart[b];
    const int total = bstart[b + 1] - beg;
    const int cl = total < CAP ? total : CAP;     // edges sorted in LDS

    if (tid < 64) cnt[tid] = 0;
    __syncthreads();
    for (int i = tid; i < cl; i += 256)
        atomicAdd(&cnt[sedge[beg + i].x & 63], 1);
    __syncthreads();
    if (tid < 64) sc[tid] = cnt[tid];
    __syncthreads();
    for (int o = 1; o < 64; o <<= 1) {
        int add = (tid < 64 && tid >= o) ? sc[tid - o] : 0;
        __syncthreads();
        if (tid < 64) sc[tid] += add;
        __syncthreads();
    }
    if (tid < 64) { off[tid] = sc[tid] - cnt[tid]; cur[tid] = sc[tid] - cnt[tid]; }
    if (tid == 63) off[64] = sc[63];
    __syncthreads();
    for (int i = tid; i < cl; i += 256) {
        const int2 e = sedge[beg + i];
        const int p = atomicAdd(&cur[e.x & 63], 1);
        ebuf[p] = e;
    }
    __syncthreads();

    const int wave = tid >> 6;
    const int lane = tid & 63;
    const int g = lane >> 4;                      // edge slot within quad
    const int c = lane & 15;                      // 16B chunk of the row
    const char* hb = (const char*)h;
    const unsigned coff = (unsigned)c << 4;       // c*16 bytes

    for (int n = wave * 16; n < wave * 16 + 16; n++) {
        const int node = b * 64 + n;
        if (node >= N) break;
        const int e0 = off[n], e1 = off[n + 1];
        float a0 = 0.f, a1 = 0.f, a2 = 0.f, a3 = 0.f;
        float a4 = 0.f, a5 = 0.f, a6 = 0.f, a7 = 0.f;

        if (e1 > e0) {
            // batch A at j = e0
            int jj = e0 + g;
            int2 eA = ebuf[jj < e1 ? jj : e0];
            float vA = (jj < e1) ? __int_as_float(eA.y) : 0.f;
            int4 hA = *(const int4*)(hb + ((((unsigned)eA.x >> 6) << 8) + coff));
            for (int j = e0;;) {
                const int jn = j + 4;
                const bool more = jn < e1;        // wave-uniform
                int2 eB; float vB = 0.f; int4 hB;
                if (more) {
                    const int j2 = jn + g;
                    eB = ebuf[j2 < e1 ? j2 : e0];
                    vB = (j2 < e1) ? __int_as_float(eB.y) : 0.f;
                    hB = *(const int4*)(hb + ((((unsigned)eB.x >> 6) << 8) + coff));
                }
                union { int4 i4; half2v h2[4]; } u; u.i4 = hA;
                a0 += vA * (float)u.h2[0].x; a1 += vA * (float)u.h2[0].y;
                a2 += vA * (float)u.h2[1].x; a3 += vA * (float)u.h2[1].y;
                a4 += vA * (float)u.h2[2].x; a5 += vA * (float)u.h2[2].y;
                a6 += vA * (float)u.h2[3].x; a7 += vA * (float)u.h2[3].y;
                if (!more) break;
                hA = hB; vA = vB; j = jn;
            }
        }
        for (int t2 = cl; t2 < total; t2++) {     // LDS overflow tail (rare)
            const int2 e = sedge[beg + t2];
            if ((e.x & 63) == n) {
                const float v = (g == 0) ? __int_as_float(e.y) : 0.f;
                union { int4 i4; half2v h2[4]; } u;
                u.i4 = *(const int4*)(hb + ((((unsigned)e.x >> 6) << 8) + coff));
                a0 += v * (float)u.h2[0].x; a1 += v * (float)u.h2[0].y;
                a2 += v * (float)u.h2[1].x; a3 += v * (float)u.h2[1].y;
                a4 += v * (float)u.h2[2].x; a5 += v * (float)u.h2[2].y;
                a6 += v * (float)u.h2[3].x; a7 += v * (float)u.h2[3].y;
            }
        }

        // butterfly reduce across the 4 edge-groups (lane bits 4,5)
        a0 += __shfl_xor(a0, 16, 64); a0 += __shfl_xor(a0, 32, 64);
        a1 += __shfl_xor(a1, 16, 64); a1 += __shfl_xor(a1, 32, 64);
        a2 += __shfl_xor(a2, 16, 64); a2 += __shfl_xor(a2, 32, 64);
        a3 += __shfl_xor(a3, 16, 64); a3 += __shfl_xor(a3, 32, 64);
        a4 += __shfl_xor(a4, 16, 64); a4 += __shfl_xor(a4, 32, 64);
        a5 += __shfl_xor(a5, 16, 64); a5 += __shfl_xor(a5, 32, 64);
        a6 += __shfl_xor(a6, 16, 64); a6 += __shfl_xor(a6, 32, 64);
        a7 += __shfl_xor(a7, 16, 64); a7 += __shfl_xor(a7, 32, 64);

        // lane (g,c) writes dims c*8 + g*2 + {0,1}
        float wx, wy;
        if (g == 0)      { wx = a0; wy = a1; }
        else if (g == 1) { wx = a2; wy = a3; }
        else if (g == 2) { wx = a4; wy = a5; }
        else             { wx = a6; wy = a7; }

        union { double d; float2 f; } bv, rv;
        const size_t oidx = (size_t)node * 64 + (unsigned)(c * 4 + g);
        bv.d = __builtin_nontemporal_load((const double*)out + oidx);
        rv.f.x = tanhf(wx + bv.f.x);
        rv.f.y = tanhf(wy + bv.f.y);
        __builtin_nontemporal_store(rv.d, (double*)out + oidx);
    }
}

// ---------------- fallback (atomic) path --------------------------------

__global__ __launch_bounds__(256)
void edge_scatter(const int* __restrict__ esrc, const int* __restrict__ edst,
                  const float* __restrict__ vals, const _Float16* __restrict__ h,
                  float* __restrict__ out, int E) {
    const int gtid = blockIdx.x * blockDim.x + threadIdx.x;
    const int wave = gtid >> 6;
    const int lane = threadIdx.x & 63;
    const int nw = (gridDim.x * blockDim.x) >> 6;
    for (int e = wave; e < E; e += nw) {
        const int s = esrc[e];
        const int d = edst[e];
        const float v = vals[e];
        const half2v hv = *(const half2v*)(h + (size_t)s * 128 + lane * 2);
        float* op = out + (size_t)d * 128 + lane * 2;
        atomicAdd(op, v * (float)hv.x);
        atomicAdd(op + 1, v * (float)hv.y);
    }
}

__global__ __launch_bounds__(256)
void tanh_kernel(float* __restrict__ out, int n4) {
    const int i = blockIdx.x * blockDim.x + threadIdx.x;
    if (i < n4) {
        float4 v = ((float4*)out)[i];
        v.x = tanhf(v.x);
        v.y = tanhf(v.y);
        v.z = tanhf(v.z);
        v.w = tanhf(v.w);
        ((float4*)out)[i] = v;
    }
}

static inline size_t align64(size_t x) { return (x + 63) & ~(size_t)63; }

extern "C" void kernel_launch(void* const* d_in, const int* in_sizes, int n_in,
                              void* d_out, int out_size, void* d_ws, size_t ws_size,
                              hipStream_t stream) {
    const float* seq    = (const float*)d_in[0];
    const int*   esrc   = (const int*)  d_in[1];
    const int*   edst   = (const int*)  d_in[2];
    const float* vals   = (const float*)d_in[3];
    const float* w_fc   = (const float*)d_in[4];
    const float* w_proj = (const float*)d_in[5];
    const float* b_proj = (const float*)d_in[6];
    const float* bias   = (const float*)d_in[7];
    float* out = (float*)d_out;

    const int N = in_sizes[0] / 128;
    const int E = in_sizes[1];
    const int NB = (N + 63) >> 6;
    const int L  = NB * PG;                       // histogram entries
    const int S  = (E + PG - 1) / PG;             // slice size
    const int nsb = (L + 2047) / 2048;            // scan blocks

    // workspace layout
    char* ws = (char*)d_ws;
    const size_t o_h     = 0;                                      // N*128 fp16
    const size_t o_whif  = align64(o_h    + (size_t)N * 128 * 2);
    const size_t o_wlof  = align64(o_whif + 32768);
    const size_t o_whip  = align64(o_wlof + 32768);
    const size_t o_wlop  = align64(o_whip + 32768);
    const size_t o_hc    = align64(o_wlop + 32768);                // L i32 (hist)
    const size_t o_pos   = align64(o_hc   + (size_t)L * 4);        // L i32 (scan)
    const size_t o_bs    = align64(o_pos  + (size_t)L * 4);        // NB+1 i32
    const size_t o_bsum  = align64(o_bs   + (size_t)(NB + 1) * 4); // 256 i32
    const size_t o_ebs   = align64(o_bsum + 1024);                 // 256 i32
    const size_t o_sed   = align64(o_ebs  + 1024);                 // E int2
    const size_t need    = o_sed + (size_t)E * 8;

    _Float16* h   = (_Float16*)(ws + o_h);
    short* whi_fc = (short*)(ws + o_whif);
    short* wlo_fc = (short*)(ws + o_wlof);
    short* whi_pj = (short*)(ws + o_whip);
    short* wlo_pj = (short*)(ws + o_wlop);
    int*   hcnt   = (int*)  (ws + o_hc);
    int*   pos    = (int*)  (ws + o_pos);
    int*   bstart = (int*)  (ws + o_bs);
    int*   bsum   = (int*)  (ws + o_bsum);
    int*   ebsum  = (int*)  (ws + o_ebs);
    int2*  sedge  = (int2*) (ws + o_sed);

    const int ntiles = (N + 63) / 64;
    const int mm_grid = ntiles < 512 ? ntiles : 512;

    wconv_kernel<<<32, 256, 0, stream>>>(w_fc, w_proj, whi_fc, wlo_fc, whi_pj, wlo_pj);
    mm_mfma_kernel<<<mm_grid, 256, 0, stream>>>(seq, whi_fc, wlo_fc, nullptr, nullptr, nullptr, h, N, 0, ntiles);
    mm_mfma_kernel<<<mm_grid, 256, 0, stream>>>(seq, whi_pj, wlo_pj, b_proj, bias, out, nullptr, N, 1, ntiles);

    if (ws_size >= need && NB <= NBMAX && nsb <= 256) {
        phist_kernel<<<PG, 256, 0, stream>>>(edst, hcnt, E, S, NB);
        pscan1_kernel<<<nsb, 256, 0, stream>>>(hcnt, pos, bsum, L);
        pscan2_kernel<<<1, 256, 0, stream>>>(bsum, ebsum, nsb);
        paddback_kernel<<<nsb, 256, 0, stream>>>(pos, ebsum, bstart, L, NB, E);
        pscatter_kernel<<<PG, 256, 0, stream>>>(esrc, edst, vals, pos, sedge, E, S, NB);
        aggregate_sorted<<<NB, 256, 0, stream>>>(bstart, sedge, h, out, N);
    } else {
        edge_scatter<<<8192, 256, 0, stream>>>(esrc, edst, vals, h, out, E);
        const int n4 = (N * 128) / 4;
        tanh_kernel<<<(n4 + 255) / 256, 256, 0, stream>>>(out, n4);
    }
}

// Round 5
// 318.313 us; speedup vs baseline: 1.2137x; 1.2137x over previous
//
#include <hip/hip_runtime.h>
#include <math.h>

// ---------------------------------------------------------------------------
// GCN layer: out = tanh( scatter_add(adj_vals * h[src] -> dst)
//                        + seq @ w_proj + b_proj + bias ),   h = seq @ w_fc
// N=100000, E=1600000, D=128, fp32.
// R9 -> R10 (R10b: fix nontemporal_store on HIP float2 -> store via double
// bit-pattern union, as in R8):
//  * REVERT persistent mm (R9: cold dispatch 148us, MfmaUtil 0.07%, total
//    +62us). Back to grid = ntiles, one tile per block.
//  * R9 null result: 4x bytes-in-flight left agg flat at 85-87us ->
//    NOT latency-bound; delivered ~6.2 TB/s = copy ceiling. Only byte
//    reduction helps. So: proj+bias residual ("base") now fp16 -> mm2
//    write 51.2->25.6 MB, agg fetch of residual 51.2->25.6 MB; out is
//    write-only in agg.
//  * agg keeps R9 quad-gather (16 lanes x 16B/edge, butterfly reduce).
// ---------------------------------------------------------------------------

typedef __attribute__((ext_vector_type(8))) short short8;
typedef __attribute__((ext_vector_type(4))) float float4v;
typedef __attribute__((ext_vector_type(2))) _Float16 half2v;

#define PG 256          // partition blocks (slices)
#define NBMAX 2048      // max buckets (64 nodes each)

static __device__ __forceinline__ short f2bf(float x) {
    unsigned u = __float_as_uint(x);
    unsigned r = (u + 0x7fffu + ((u >> 16) & 1u)) >> 16;   // RNE
    return (short)r;
}
static __device__ __forceinline__ float bf2f(short h) {
    return __uint_as_float(((unsigned)(unsigned short)h) << 16);
}

// ---------------- W pre-conversion: w[k][c] fp32 -> whi/wlo[c][k] bf16 ------
// One launch converts both weight matrices (blocks 0-15: w_fc, 16-31: w_proj).
__global__ __launch_bounds__(256)
void wconv_kernel(const float* __restrict__ wa, const float* __restrict__ wb,
                  short* __restrict__ whia, short* __restrict__ wloa,
                  short* __restrict__ whib, short* __restrict__ wlob) {
    const int bb = blockIdx.x;
    const float* w  = (bb < 16) ? wa   : wb;
    short* whi      = (bb < 16) ? whia : whib;
    short* wlo      = (bb < 16) ? wloa : wlob;
    const int i = (bb & 15) * 256 + threadIdx.x;    // 4096 float4s
    const float4 v = ((const float4*)w)[i];
    const int k = i >> 5;
    const int c4 = (i & 31) * 4;
    float xs[4] = {v.x, v.y, v.z, v.w};
    #pragma unroll
    for (int j = 0; j < 4; j++) {
        const short hi = f2bf(xs[j]);
        const short lo = f2bf(xs[j] - bf2f(hi));
        whi[(c4 + j) * 128 + k] = hi;
        wlo[(c4 + j) * 128 + k] = lo;
    }
}

// ---------------- MFMA matmul: out[N x 128] = seq[N x 128] @ w[128 x 128] ---
// A*B ~= Ah*Bh + Ah*Bl + Al*Bh (split bf16, rel err ~1e-5).
// out16 != nullptr -> store fp16 (h path: add_bias=0; base path: add_bias=1);
// else fp32 + bias (fallback path).
#define KP 136

__global__ __launch_bounds__(256, 2)
void mm_mfma_kernel(const float* __restrict__ seq, const short* __restrict__ whi,
                    const short* __restrict__ wlo,
                    const float* __restrict__ b0p, const float* __restrict__ b1p,
                    float* __restrict__ out, _Float16* __restrict__ out16,
                    int N, int add_bias) {
    __shared__ short wt_hi[128 * KP];
    __shared__ short wt_lo[128 * KP];

    const int tid = threadIdx.x;
    for (int i = tid; i < 2048; i += 256) {
        const int row = i >> 4;
        const int k8  = (i & 15) * 8;
        *(float4*)&wt_hi[row * KP + k8] = ((const float4*)whi)[i];
        *(float4*)&wt_lo[row * KP + k8] = ((const float4*)wlo)[i];
    }
    __syncthreads();

    const int wave = tid >> 6;
    const int lane = tid & 63;
    const int q = lane >> 4;
    const int c = lane & 15;
    const int R = blockIdx.x * 64 + wave * 16;
    const int rowL = (R + c < N) ? (R + c) : (N - 1);

    float4v acc[8];
    #pragma unroll
    for (int ct = 0; ct < 8; ct++) acc[ct] = (float4v){0.f, 0.f, 0.f, 0.f};

    #pragma unroll
    for (int t = 0; t < 4; t++) {
        const int kk = t * 32 + q * 8;
        const float4 a0 = *(const float4*)&seq[(size_t)rowL * 128 + kk];
        const float4 a1 = *(const float4*)&seq[(size_t)rowL * 128 + kk + 4];
        float xs[8] = {a0.x, a0.y, a0.z, a0.w, a1.x, a1.y, a1.z, a1.w};
        union { short s[8]; short8 v; } ahi, alo;
        #pragma unroll
        for (int j = 0; j < 8; j++) {
            const short hi = f2bf(xs[j]);
            ahi.s[j] = hi;
            alo.s[j] = f2bf(xs[j] - bf2f(hi));
        }
        #pragma unroll
        for (int ct = 0; ct < 8; ct++) {
            const int n = ct * 16 + c;
            const short8 bhi = *(const short8*)&wt_hi[n * KP + kk];
            const short8 blo = *(const short8*)&wt_lo[n * KP + kk];
            acc[ct] = __builtin_amdgcn_mfma_f32_16x16x32_bf16(ahi.v, bhi, acc[ct], 0, 0, 0);
            acc[ct] = __builtin_amdgcn_mfma_f32_16x16x32_bf16(ahi.v, blo, acc[ct], 0, 0, 0);
            acc[ct] = __builtin_amdgcn_mfma_f32_16x16x32_bf16(alo.v, bhi, acc[ct], 0, 0, 0);
        }
    }

    if (out16) {
        #pragma unroll
        for (int ct = 0; ct < 8; ct++) {
            const int col = ct * 16 + c;
            float badd = 0.f;
            if (add_bias) badd = b0p[col] + b1p[col];
            #pragma unroll
            for (int r = 0; r < 4; r++) {
                const int row = R + q * 4 + r;
                if (row < N) out16[(size_t)row * 128 + col] = (_Float16)(acc[ct][r] + badd);
            }
        }
    } else {
        #pragma unroll
        for (int ct = 0; ct < 8; ct++) {
            const int col = ct * 16 + c;
            float badd = 0.f;
            if (add_bias) badd = b0p[col] + b1p[col];
            #pragma unroll
            for (int r = 0; r < 4; r++) {
                const int row = R + q * 4 + r;
                if (row < N) out[(size_t)row * 128 + col] = acc[ct][r] + badd;
            }
        }
    }
}

// ---------------- atomic-free radix partition (bucket = dst>>6) ------------

// Per-slice LDS histogram -> hcnt[b*PG + g] (bucket-major for the scan).
__global__ __launch_bounds__(256)
void phist_kernel(const int* __restrict__ edst, int* __restrict__ hcnt,
                  int E, int S, int NB) {
    __shared__ int cnt[NBMAX];
    const int g = blockIdx.x;
    const int tid = threadIdx.x;
    for (int b = tid; b < NB; b += 256) cnt[b] = 0;
    __syncthreads();
    const int lo = g * S;
    const int hi = (lo + S < E) ? (lo + S) : E;
    for (int i = lo + tid; i < hi; i += 256)
        atomicAdd(&cnt[edst[i] >> 6], 1);
    __syncthreads();
    for (int b = tid; b < NB; b += 256) hcnt[b * PG + g] = cnt[b];
}

// Exclusive scan over L = NB*PG entries. pscan1: per-block (2048 elems)
// exclusive prefix + block sums.
__global__ __launch_bounds__(256)
void pscan1_kernel(const int* __restrict__ in, int* __restrict__ out,
                   int* __restrict__ bsum, int L) {
    __shared__ int s[256];
    const int t = threadIdx.x;
    const int base = blockIdx.x * 2048 + t * 8;
    int v[8];
    int mysum = 0;
    #pragma unroll
    for (int j = 0; j < 8; j++) {
        v[j] = (base + j < L) ? in[base + j] : 0;
        mysum += v[j];
    }
    s[t] = mysum;
    __syncthreads();
    for (int o = 1; o < 256; o <<= 1) {
        int add = (t >= o) ? s[t - o] : 0;
        __syncthreads();
        s[t] += add;
        __syncthreads();
    }
    int run = s[t] - mysum;
    #pragma unroll
    for (int j = 0; j < 8; j++) {
        if (base + j < L) out[base + j] = run;
        run += v[j];
    }
    if (t == 255) bsum[blockIdx.x] = s[255];
}

// Single block: exclusive scan of nb (<=256) block sums.
__global__ __launch_bounds__(256)
void pscan2_kernel(const int* __restrict__ bsum, int* __restrict__ ebsum, int nb) {
    __shared__ int s[256];
    const int t = threadIdx.x;
    const int v = (t < nb) ? bsum[t] : 0;
    s[t] = v;
    __syncthreads();
    for (int o = 1; o < 256; o <<= 1) {
        int add = (t >= o) ? s[t - o] : 0;
        __syncthreads();
        s[t] += add;
        __syncthreads();
    }
    if (t < nb) ebsum[t] = s[t] - v;
}

// pos[i] += ebsum[block]; also emit bstart[b] = pos[b*PG] and bstart[NB] = E.
__global__ __launch_bounds__(256)
void paddback_kernel(int* __restrict__ pos, const int* __restrict__ ebsum,
                     int* __restrict__ bstart, int L, int NB, int E) {
    const int add = ebsum[blockIdx.x];
    const int base = blockIdx.x * 2048 + threadIdx.x * 8;
    #pragma unroll
    for (int j = 0; j < 8; j++) {
        const int idx = base + j;
        if (idx < L) {
            const int v = pos[idx] + add;
            pos[idx] = v;
            if ((idx & (PG - 1)) == 0) bstart[idx / PG] = v;
        }
    }
    if (blockIdx.x == 0 && threadIdx.x == 0) bstart[NB] = E;
}

// Atomic-free (global) scatter: LDS cursors seeded from pos.
// entry = (src<<6 | dst&63, val) : 8B.
__global__ __launch_bounds__(256)
void pscatter_kernel(const int* __restrict__ esrc, const int* __restrict__ edst,
                     const float* __restrict__ vals, const int* __restrict__ pos,
                     int2* __restrict__ sedge, int E, int S, int NB) {
    __shared__ int cur[NBMAX];
    const int g = blockIdx.x;
    const int tid = threadIdx.x;
    for (int b = tid; b < NB; b += 256) cur[b] = pos[b * PG + g];
    __syncthreads();
    const int lo = g * S;
    const int hi = (lo + S < E) ? (lo + S) : E;
    for (int i = lo + tid; i < hi; i += 256) {
        const int d = edst[i];
        const int p = atomicAdd(&cur[d >> 6], 1);
        sedge[p] = make_int2((esrc[i] << 6) | (d & 63), __float_as_int(vals[i]));
    }
}

// One block (256 thr) per 64-node bucket. Counting-sort edges by node into
// LDS (16KB), then each wave aggregates 16 nodes. Gather layout: 16 lanes
// per edge row (16B each), 4 edges per dwordx4 instruction, 1-batch software
// pipeline; group-reduce via shfl_xor(16/32) butterfly. Residual read from
// fp16 base; fused tanh; out is WRITE-ONLY (non-temporal, via double union).
#define CAP 2048

__global__ __launch_bounds__(256, 8)
void aggregate_sorted(const int* __restrict__ bstart, const int2* __restrict__ sedge,
                      const _Float16* __restrict__ h, const _Float16* __restrict__ base,
                      float* __restrict__ out, int N) {
    __shared__ int2 ebuf[CAP];
    __shared__ int cnt[64], sc[64], off[65], cur[64];
    const int b = blockIdx.x;
    const int tid = threadIdx.x;
    const int beg = bstart[b];
    const int total = bstart[b + 1] - beg;
    const int cl = total < CAP ? total : CAP;     // edges sorted in LDS

    if (tid < 64) cnt[tid] = 0;
    __syncthreads();
    for (int i = tid; i < cl; i += 256)
        atomicAdd(&cnt[sedge[beg + i].x & 63], 1);
    __syncthreads();
    if (tid < 64) sc[tid] = cnt[tid];
    __syncthreads();
    for (int o = 1; o < 64; o <<= 1) {
        int add = (tid < 64 && tid >= o) ? sc[tid - o] : 0;
        __syncthreads();
        if (tid < 64) sc[tid] += add;
        __syncthreads();
    }
    if (tid < 64) { off[tid] = sc[tid] - cnt[tid]; cur[tid] = sc[tid] - cnt[tid]; }
    if (tid == 63) off[64] = sc[63];
    __syncthreads();
    for (int i = tid; i < cl; i += 256) {
        const int2 e = sedge[beg + i];
        const int p = atomicAdd(&cur[e.x & 63], 1);
        ebuf[p] = e;
    }
    __syncthreads();

    const int wave = tid >> 6;
    const int lane = tid & 63;
    const int g = lane >> 4;                      // edge slot within quad
    const int c = lane & 15;                      // 16B chunk of the row
    const char* hb = (const char*)h;
    const unsigned coff = (unsigned)c << 4;       // c*16 bytes

    for (int n = wave * 16; n < wave * 16 + 16; n++) {
        const int node = b * 64 + n;
        if (node >= N) break;
        const int e0 = off[n], e1 = off[n + 1];
        float a0 = 0.f, a1 = 0.f, a2 = 0.f, a3 = 0.f;
        float a4 = 0.f, a5 = 0.f, a6 = 0.f, a7 = 0.f;

        if (e1 > e0) {
            // batch A at j = e0
            int jj = e0 + g;
            int2 eA = ebuf[jj < e1 ? jj : e0];
            float vA = (jj < e1) ? __int_as_float(eA.y) : 0.f;
            int4 hA = *(const int4*)(hb + ((((unsigned)eA.x >> 6) << 8) + coff));
            for (int j = e0;;) {
                const int jn = j + 4;
                const bool more = jn < e1;        // wave-uniform
                int2 eB; float vB = 0.f; int4 hB;
                if (more) {
                    const int j2 = jn + g;
                    eB = ebuf[j2 < e1 ? j2 : e0];
                    vB = (j2 < e1) ? __int_as_float(eB.y) : 0.f;
                    hB = *(const int4*)(hb + ((((unsigned)eB.x >> 6) << 8) + coff));
                }
                union { int4 i4; half2v h2[4]; } u; u.i4 = hA;
                a0 += vA * (float)u.h2[0].x; a1 += vA * (float)u.h2[0].y;
                a2 += vA * (float)u.h2[1].x; a3 += vA * (float)u.h2[1].y;
                a4 += vA * (float)u.h2[2].x; a5 += vA * (float)u.h2[2].y;
                a6 += vA * (float)u.h2[3].x; a7 += vA * (float)u.h2[3].y;
                if (!more) break;
                hA = hB; vA = vB; j = jn;
            }
        }
        for (int t2 = cl; t2 < total; t2++) {     // LDS overflow tail (rare)
            const int2 e = sedge[beg + t2];
            if ((e.x & 63) == n) {
                const float v = (g == 0) ? __int_as_float(e.y) : 0.f;
                union { int4 i4; half2v h2[4]; } u;
                u.i4 = *(const int4*)(hb + ((((unsigned)e.x >> 6) << 8) + coff));
                a0 += v * (float)u.h2[0].x; a1 += v * (float)u.h2[0].y;
                a2 += v * (float)u.h2[1].x; a3 += v * (float)u.h2[1].y;
                a4 += v * (float)u.h2[2].x; a5 += v * (float)u.h2[2].y;
                a6 += v * (float)u.h2[3].x; a7 += v * (float)u.h2[3].y;
            }
        }

        // butterfly reduce across the 4 edge-groups (lane bits 4,5)
        a0 += __shfl_xor(a0, 16, 64); a0 += __shfl_xor(a0, 32, 64);
        a1 += __shfl_xor(a1, 16, 64); a1 += __shfl_xor(a1, 32, 64);
        a2 += __shfl_xor(a2, 16, 64); a2 += __shfl_xor(a2, 32, 64);
        a3 += __shfl_xor(a3, 16, 64); a3 += __shfl_xor(a3, 32, 64);
        a4 += __shfl_xor(a4, 16, 64); a4 += __shfl_xor(a4, 32, 64);
        a5 += __shfl_xor(a5, 16, 64); a5 += __shfl_xor(a5, 32, 64);
        a6 += __shfl_xor(a6, 16, 64); a6 += __shfl_xor(a6, 32, 64);
        a7 += __shfl_xor(a7, 16, 64); a7 += __shfl_xor(a7, 32, 64);

        // lane (g,c) owns dims c*8 + g*2 + {0,1}
        float wx, wy;
        if (g == 0)      { wx = a0; wy = a1; }
        else if (g == 1) { wx = a2; wy = a3; }
        else if (g == 2) { wx = a4; wy = a5; }
        else             { wx = a6; wy = a7; }

        const half2v bb = __builtin_nontemporal_load(
            (const half2v*)(base + (size_t)node * 128 + (unsigned)(c * 8 + g * 2)));
        union { double d; float2 f; } rv;
        rv.f.x = tanhf(wx + (float)bb.x);
        rv.f.y = tanhf(wy + (float)bb.y);
        __builtin_nontemporal_store(rv.d, (double*)out + (size_t)node * 64 + (unsigned)(c * 4 + g));
    }
}

// ---------------- fallback (atomic) path --------------------------------

__global__ __launch_bounds__(256)
void edge_scatter(const int* __restrict__ esrc, const int* __restrict__ edst,
                  const float* __restrict__ vals, const _Float16* __restrict__ h,
                  float* __restrict__ out, int E) {
    const int gtid = blockIdx.x * blockDim.x + threadIdx.x;
    const int wave = gtid >> 6;
    const int lane = threadIdx.x & 63;
    const int nw = (gridDim.x * blockDim.x) >> 6;
    for (int e = wave; e < E; e += nw) {
        const int s = esrc[e];
        const int d = edst[e];
        const float v = vals[e];
        const half2v hv = *(const half2v*)(h + (size_t)s * 128 + lane * 2);
        float* op = out + (size_t)d * 128 + lane * 2;
        atomicAdd(op, v * (float)hv.x);
        atomicAdd(op + 1, v * (float)hv.y);
    }
}

__global__ __launch_bounds__(256)
void tanh_kernel(float* __restrict__ out, int n4) {
    const int i = blockIdx.x * blockDim.x + threadIdx.x;
    if (i < n4) {
        float4 v = ((float4*)out)[i];
        v.x = tanhf(v.x);
        v.y = tanhf(v.y);
        v.z = tanhf(v.z);
        v.w = tanhf(v.w);
        ((float4*)out)[i] = v;
    }
}

static inline size_t align64(size_t x) { return (x + 63) & ~(size_t)63; }

extern "C" void kernel_launch(void* const* d_in, const int* in_sizes, int n_in,
                              void* d_out, int out_size, void* d_ws, size_t ws_size,
                              hipStream_t stream) {
    const float* seq    = (const float*)d_in[0];
    const int*   esrc   = (const int*)  d_in[1];
    const int*   edst   = (const int*)  d_in[2];
    const float* vals   = (const float*)d_in[3];
    const float* w_fc   = (const float*)d_in[4];
    const float* w_proj = (const float*)d_in[5];
    const float* b_proj = (const float*)d_in[6];
    const float* bias   = (const float*)d_in[7];
    float* out = (float*)d_out;

    const int N = in_sizes[0] / 128;
    const int E = in_sizes[1];
    const int NB = (N + 63) >> 6;
    const int L  = NB * PG;                       // histogram entries
    const int S  = (E + PG - 1) / PG;             // slice size
    const int nsb = (L + 2047) / 2048;            // scan blocks

    // workspace layout
    char* ws = (char*)d_ws;
    const size_t o_h     = 0;                                      // N*128 fp16
    const size_t o_b16   = align64(o_h    + (size_t)N * 128 * 2);  // N*128 fp16
    const size_t o_whif  = align64(o_b16  + (size_t)N * 128 * 2);
    const size_t o_wlof  = align64(o_whif + 32768);
    const size_t o_whip  = align64(o_wlof + 32768);
    const size_t o_wlop  = align64(o_whip + 32768);
    const size_t o_hc    = align64(o_wlop + 32768);                // L i32 (hist)
    const size_t o_pos   = align64(o_hc   + (size_t)L * 4);        // L i32 (scan)
    const size_t o_bs    = align64(o_pos  + (size_t)L * 4);        // NB+1 i32
    const size_t o_bsum  = align64(o_bs   + (size_t)(NB + 1) * 4); // 256 i32
    const size_t o_ebs   = align64(o_bsum + 1024);                 // 256 i32
    const size_t o_sed   = align64(o_ebs  + 1024);                 // E int2
    const size_t need    = o_sed + (size_t)E * 8;

    _Float16* h      = (_Float16*)(ws + o_h);
    _Float16* base16 = (_Float16*)(ws + o_b16);
    short* whi_fc = (short*)(ws + o_whif);
    short* wlo_fc = (short*)(ws + o_wlof);
    short* whi_pj = (short*)(ws + o_whip);
    short* wlo_pj = (short*)(ws + o_wlop);
    int*   hcnt   = (int*)  (ws + o_hc);
    int*   pos    = (int*)  (ws + o_pos);
    int*   bstart = (int*)  (ws + o_bs);
    int*   bsum   = (int*)  (ws + o_bsum);
    int*   ebsum  = (int*)  (ws + o_ebs);
    int2*  sedge  = (int2*) (ws + o_sed);

    const int mm_blocks = (N + 63) / 64;
    const bool sorted_ok = (ws_size >= need && NB <= NBMAX && nsb <= 256);

    wconv_kernel<<<32, 256, 0, stream>>>(w_fc, w_proj, whi_fc, wlo_fc, whi_pj, wlo_pj);
    mm_mfma_kernel<<<mm_blocks, 256, 0, stream>>>(seq, whi_fc, wlo_fc, nullptr, nullptr, nullptr, h, N, 0);

    if (sorted_ok) {
        // proj+biases -> fp16 base (read by agg; out becomes write-only)
        mm_mfma_kernel<<<mm_blocks, 256, 0, stream>>>(seq, whi_pj, wlo_pj, b_proj, bias, nullptr, base16, N, 1);
        phist_kernel<<<PG, 256, 0, stream>>>(edst, hcnt, E, S, NB);
        pscan1_kernel<<<nsb, 256, 0, stream>>>(hcnt, pos, bsum, L);
        pscan2_kernel<<<1, 256, 0, stream>>>(bsum, ebsum, nsb);
        paddback_kernel<<<nsb, 256, 0, stream>>>(pos, ebsum, bstart, L, NB, E);
        pscatter_kernel<<<PG, 256, 0, stream>>>(esrc, edst, vals, pos, sedge, E, S, NB);
        aggregate_sorted<<<NB, 256, 0, stream>>>(bstart, sedge, h, base16, out, N);
    } else {
        mm_mfma_kernel<<<mm_blocks, 256, 0, stream>>>(seq, whi_pj, wlo_pj, b_proj, bias, out, nullptr, N, 1);
        edge_scatter<<<8192, 256, 0, stream>>>(esrc, edst, vals, h, out, E);
        const int n4 = (N * 128) / 4;
        tanh_kernel<<<(n4 + 255) / 256, 256, 0, stream>>>(out, n4);
    }
}